// Round 1
// baseline (71.654 us; speedup 1.0000x reference)
//
#include <hip/hip_runtime.h>

// loss[b] = (beta1 - beta2)^2 - intersection
//   true: (B,4,4) fp32, box i = (minx,miny,maxx,maxy)
//   pred: (B,10,3) fp32, only first 4 rows used: (p0,p1,p2) ->
//         mnx=min(p0,p2), mxx=max(p0,p2), mny=p1, mxy=p1+(mxx-mnx)
//   overlap(la,ha,lb,hb) = max(0, min(ha,hb)-max(la,lb))
//   inter = sum_ij ox(t_i,p_j)*oy(t_i,p_j)
//   beta  = sum_ij area_ij  (area_ii squared), area from self-overlaps

__global__ __launch_bounds__(256) void boxloss_kernel(
    const float* __restrict__ T, const float* __restrict__ P,
    float* __restrict__ out, int B)
{
    int b = blockIdx.x * blockDim.x + threadIdx.x;
    if (b >= B) return;

    // ---- load true: 4x float4, 64B-aligned per batch ----
    float tmnx[4], tmny[4], tmxx[4], tmxy[4];
    const float4* T4 = reinterpret_cast<const float4*>(T) + (size_t)b * 4;
    #pragma unroll
    for (int i = 0; i < 4; ++i) {
        float4 t = T4[i];
        tmnx[i] = t.x; tmny[i] = t.y; tmxx[i] = t.z; tmxy[i] = t.w;
    }

    // ---- load pred[:4,:3]: 6x float2 (b*120 bytes is 8B-aligned) ----
    const float2* P2 = reinterpret_cast<const float2*>(P + (size_t)b * 30);
    float f[12];
    #pragma unroll
    for (int k = 0; k < 6; ++k) {
        float2 q = P2[k];
        f[2 * k] = q.x; f[2 * k + 1] = q.y;
    }
    float pmnx[4], pmny[4], pmxx[4], pmxy[4];
    #pragma unroll
    for (int j = 0; j < 4; ++j) {
        float p0 = f[3 * j], p1 = f[3 * j + 1], p2 = f[3 * j + 2];
        float mn = fminf(p0, p2), mx = fmaxf(p0, p2);
        pmnx[j] = mn; pmxx[j] = mx; pmny[j] = p1; pmxy[j] = p1 + (mx - mn);
    }

    // ---- 4x4 reductions ----
    float inter = 0.f, b1 = 0.f, b2 = 0.f;
    #pragma unroll
    for (int i = 0; i < 4; ++i) {
        #pragma unroll
        for (int j = 0; j < 4; ++j) {
            // cross overlap (true_i vs pred_j)
            float xo = fmaxf(0.f, fminf(tmxx[i], pmxx[j]) - fmaxf(tmnx[i], pmnx[j]));
            float yo = fmaxf(0.f, fminf(tmxy[i], pmxy[j]) - fmaxf(tmny[i], pmny[j]));
            inter += xo * yo;
            // self overlap true
            float x1 = fmaxf(0.f, fminf(tmxx[i], tmxx[j]) - fmaxf(tmnx[i], tmnx[j]));
            float y1 = fmaxf(0.f, fminf(tmxy[i], tmxy[j]) - fmaxf(tmny[i], tmny[j]));
            float a1 = x1 * y1;
            // self overlap pred
            float x2 = fmaxf(0.f, fminf(pmxx[i], pmxx[j]) - fmaxf(pmnx[i], pmnx[j]));
            float y2 = fmaxf(0.f, fminf(pmxy[i], pmxy[j]) - fmaxf(pmny[i], pmny[j]));
            float a2 = x2 * y2;
            b1 += (i == j) ? a1 * a1 : a1;
            b2 += (i == j) ? a2 * a2 : a2;
        }
    }
    float d = b1 - b2;
    out[b] = d * d - inter;
}

extern "C" void kernel_launch(void* const* d_in, const int* in_sizes, int n_in,
                              void* d_out, int out_size, void* d_ws, size_t ws_size,
                              hipStream_t stream)
{
    const float* T = (const float*)d_in[0];   // true: B*16 floats
    const float* P = (const float*)d_in[1];   // pred: B*30 floats
    float* out = (float*)d_out;               // B floats
    int B = in_sizes[0] / 16;

    int block = 256;
    int grid = (B + block - 1) / block;
    boxloss_kernel<<<grid, block, 0, stream>>>(T, P, out, B);
}